// Round 5
// baseline (3035.318 us; speedup 1.0000x reference)
//
#include <hip/hip_runtime.h>
#include <hip/hip_bf16.h>
#include <math.h>

// Problem constants
#define Bq   8
#define NPix 10000
#define HH   100
#define WW   100
#define Dm   256
#define NH   8
#define HD   32
#define PTS  4
#define FFd  1024
#define Lnum 6
#define Mrows (Bq * NPix)   // 80000

typedef short bf16x8 __attribute__((ext_vector_type(8)));
typedef short short4v __attribute__((ext_vector_type(4)));
typedef float f32x4 __attribute__((ext_vector_type(4)));

__device__ __forceinline__ float bf2f(unsigned short u) {
    return __uint_as_float(((unsigned)u) << 16);
}
__device__ __forceinline__ unsigned short f2bf(float f) {
    unsigned x = __float_as_uint(f);
    return (unsigned short)((x + 0x7fffu + ((x >> 16) & 1u)) >> 16);  // RNE
}

// ---------------------------------------------------------------------------
// Positional encoding + add: x (fp32) and xb (bf16) = src + pe
// ---------------------------------------------------------------------------
__global__ __launch_bounds__(256) void pos_add_kernel(
    const float* __restrict__ src, float* __restrict__ x, short* __restrict__ xb)
{
    int idx = blockIdx.x * 256 + threadIdx.x;
    int c = idx & (Dm - 1);
    int n = (idx >> 8) % NPix;
    int cc = c;
    float coord;
    if (c < 128) { coord = (float)(n / WW); }
    else         { coord = (float)(n % WW); cc = c - 128; }
    int j = cc >> 1;
    float f = __expf(-logf(10000.0f) * (2.0f * (float)j) / 128.0f);
    float arg = coord * f;
    float pe = (cc & 1) ? cosf(arg) : sinf(arg);
    float val = src[idx] + pe;
    x[idx] = val;
    xb[idx] = (short)f2bf(val);
}

// ---------------------------------------------------------------------------
// Weight repack: W[l][K][N] fp32 -> Wt[l][nOff + n][K] bf16 (transpose)
// ---------------------------------------------------------------------------
__global__ __launch_bounds__(256) void repack_kernel(
    const float* __restrict__ W, short* __restrict__ Wt,
    int K, int N, int outLstride, int nOff)
{
    __shared__ float t[64][65];
    int l  = blockIdx.z;
    int k0 = blockIdx.y * 64, n0 = blockIdx.x * 64;
    const float* Wl = W + (size_t)l * K * N;
    for (int i = threadIdx.x; i < 64 * 64; i += 256) {
        int kk = i >> 6, nn = i & 63;
        float val = 0.0f;
        if (k0 + kk < K && n0 + nn < N) val = Wl[(size_t)(k0 + kk) * N + (n0 + nn)];
        t[kk][nn] = val;
    }
    __syncthreads();
    for (int i = threadIdx.x; i < 64 * 64; i += 256) {
        int nn = i >> 6, kk = i & 63;
        if (n0 + nn < N && k0 + kk < K)
            Wt[(size_t)l * outLstride + (size_t)(nOff + n0 + nn) * K + (k0 + kk)]
                = (short)f2bf(t[kk][nn]);
    }
}

// combined bias: bcat[l][352] = bv(256) | boff(64) | ba(32)
__global__ void bcat_kernel(const float* __restrict__ bv,
                            const float* __restrict__ boff,
                            const float* __restrict__ ba,
                            float* __restrict__ bcat)
{
    int l = blockIdx.x, c = threadIdx.x;
    float v;
    if (c < 256)      v = bv[l * 256 + c];
    else if (c < 320) v = boff[l * 64 + (c - 256)];
    else              v = ba[l * 32 + (c - 320)];
    bcat[l * 352 + c] = v;
}

// ---------------------------------------------------------------------------
// bf16 MFMA GEMM, 128x128 tile, 4 waves, BK=64. (WvWc path, MODE 2 split out)
// ---------------------------------------------------------------------------
template<bool GELU, int MODE>
__global__ __launch_bounds__(256) void gemm_mfma_kernel(
    const short* __restrict__ A, const short* __restrict__ Bt,
    const float* __restrict__ bias, void* __restrict__ Cv,
    float* __restrict__ C2,
    int M, int K, int Nc, int ldc)
{
    __shared__ short As[128 * 64];
    __shared__ short Bs[128 * 64];
    const int tid = threadIdx.x;

    int nwg  = gridDim.x * gridDim.y;
    int orig = blockIdx.y * gridDim.x + blockIdx.x;
    int xcd  = orig & 7, pos = orig >> 3;
    int q = nwg >> 3, r = nwg & 7;
    int flat = (xcd < r ? xcd * (q + 1) : r * (q + 1) + (xcd - r) * q) + pos;
    const int bm = (flat / gridDim.x) * 128;
    const int bn = (flat % gridDim.x) * 128;

    const int w = tid >> 6, l = tid & 63;
    const int wr = (w >> 1) * 64, wc = (w & 1) * 64;

    f32x4 acc[4][4];
    #pragma unroll
    for (int m = 0; m < 4; ++m)
        #pragma unroll
        for (int n = 0; n < 4; ++n)
            #pragma unroll
            for (int j = 0; j < 4; ++j) acc[m][n][j] = 0.0f;

    const int rl = tid >> 3;
    const int cl = tid & 7;
    const int lr = l & 15, lq = l >> 4;

    for (int k0 = 0; k0 < K; k0 += 64) {
        #pragma unroll
        for (int p = 0; p < 4; ++p) {
            int row = p * 32 + rl;
            int sc  = cl ^ (row & 7);
            int ga  = bm + row; if (ga > M - 1) ga = M - 1;
            __builtin_amdgcn_global_load_lds((const void*)(A + (size_t)ga * K + k0 + sc * 8),
                (void*)&As[(p * 32 + w * 8) * 64], 16, 0, 0);
            int gb = bn + row; if (gb > Nc - 1) gb = Nc - 1;
            __builtin_amdgcn_global_load_lds((const void*)(Bt + (size_t)gb * K + k0 + sc * 8),
                (void*)&Bs[(p * 32 + w * 8) * 64], 16, 0, 0);
        }
        __syncthreads();

        #pragma unroll
        for (int ks = 0; ks < 2; ++ks) {
            bf16x8 af[4], bfr[4];
            #pragma unroll
            for (int m = 0; m < 4; ++m) {
                int row = wr + m * 16 + lr;
                int ch  = (ks * 4 + lq) ^ (row & 7);
                af[m] = *(const bf16x8*)&As[row * 64 + ch * 8];
            }
            #pragma unroll
            for (int n = 0; n < 4; ++n) {
                int row = wc + n * 16 + lr;
                int ch  = (ks * 4 + lq) ^ (row & 7);
                bfr[n] = *(const bf16x8*)&Bs[row * 64 + ch * 8];
            }
            #pragma unroll
            for (int m = 0; m < 4; ++m)
                #pragma unroll
                for (int n = 0; n < 4; ++n)
                    acc[m][n] = __builtin_amdgcn_mfma_f32_16x16x32_bf16(
                        af[m], bfr[n], acc[m][n], 0, 0, 0);
        }
        __syncthreads();
    }

    #pragma unroll
    for (int m = 0; m < 4; ++m) {
        int row0 = bm + wr + m * 16 + lq * 4;
        #pragma unroll
        for (int n = 0; n < 4; ++n) {
            int col = bn + wc + n * 16 + lr;
            if (col >= Nc) continue;
            float bi = bias[col];
            #pragma unroll
            for (int j = 0; j < 4; ++j) {
                int rr = row0 + j;
                if (rr >= M) continue;
                float val = acc[m][n][j] + bi;
                if (GELU)
                    val = 0.5f * val * (1.0f + erff(val * 0.70710678118654752f));
                if (MODE == 1) {
                    ((short*)Cv)[(size_t)rr * ldc + col] = (short)f2bf(val);
                } else {
                    if (col < 256)
                        ((short*)Cv)[(size_t)rr * 256 + col] = (short)f2bf(val);
                    else
                        C2[(size_t)rr * 96 + (col - 256)] = val;
                }
            }
        }
    }
}

// ---------------------------------------------------------------------------
// bf16 MFMA GEMM + fused residual+LayerNorm epilogue (Wo path, K=256).
// BM=64, BN=256, 4 waves; wave owns 16 rows x 256 cols.
// ---------------------------------------------------------------------------
__global__ __launch_bounds__(256) void gemm_ln_kernel(
    const short* __restrict__ A, const short* __restrict__ Bt,
    const float* __restrict__ bias,
    const float* __restrict__ gw, const float* __restrict__ bw,
    float* __restrict__ x, short* __restrict__ xb,
    int M, int K)
{
    __shared__ short As[64 * 64];
    __shared__ short Bs[256 * 64];
    const int tid = threadIdx.x;
    const int bm = blockIdx.x * 64;
    const int w = tid >> 6, l = tid & 63;
    const int rl = tid >> 3, cl = tid & 7;
    const int lr = l & 15, lq = l >> 4;

    f32x4 acc[16];
    #pragma unroll
    for (int n = 0; n < 16; ++n)
        #pragma unroll
        for (int j = 0; j < 4; ++j) acc[n][j] = 0.0f;

    for (int k0 = 0; k0 < K; k0 += 64) {
        #pragma unroll
        for (int p = 0; p < 2; ++p) {
            int row = p * 32 + rl;
            int sc  = cl ^ (row & 7);
            int ga  = bm + row; if (ga > M - 1) ga = M - 1;
            __builtin_amdgcn_global_load_lds((const void*)(A + (size_t)ga * K + k0 + sc * 8),
                (void*)&As[(p * 32 + w * 8) * 64], 16, 0, 0);
        }
        #pragma unroll
        for (int p = 0; p < 8; ++p) {
            int row = p * 32 + rl;
            int sc  = cl ^ (row & 7);
            __builtin_amdgcn_global_load_lds((const void*)(Bt + (size_t)row * K + k0 + sc * 8),
                (void*)&Bs[(p * 32 + w * 8) * 64], 16, 0, 0);
        }
        __syncthreads();

        #pragma unroll
        for (int ks = 0; ks < 2; ++ks) {
            int arow = w * 16 + lr;
            bf16x8 af = *(const bf16x8*)&As[arow * 64 + (((ks * 4 + lq) ^ (arow & 7))) * 8];
            #pragma unroll
            for (int hb = 0; hb < 2; ++hb) {
                bf16x8 bfr[8];
                #pragma unroll
                for (int i = 0; i < 8; ++i) {
                    int brow = (hb * 8 + i) * 16 + lr;
                    bfr[i] = *(const bf16x8*)&Bs[brow * 64 + (((ks * 4 + lq) ^ (brow & 7))) * 8];
                }
                #pragma unroll
                for (int i = 0; i < 8; ++i)
                    acc[hb * 8 + i] = __builtin_amdgcn_mfma_f32_16x16x32_bf16(
                        af, bfr[i], acc[hb * 8 + i], 0, 0, 0);
            }
        }
        __syncthreads();
    }

    float bi[16];
    #pragma unroll
    for (int n = 0; n < 16; ++n) bi[n] = bias[n * 16 + lr];

    #pragma unroll
    for (int j = 0; j < 4; ++j) {
        int rr = bm + w * 16 + lq * 4 + j;
        if (rr < M) {
            float tmp[16];
            float sum = 0.0f;
            #pragma unroll
            for (int n = 0; n < 16; ++n) {
                int c = n * 16 + lr;
                float val = acc[n][j] + bi[n] + x[(size_t)rr * 256 + c];
                tmp[n] = val;
                sum += val;
            }
            #pragma unroll
            for (int o = 8; o >= 1; o >>= 1) sum += __shfl_xor(sum, o);
            float mean = sum * (1.0f / 256.0f);
            float vs = 0.0f;
            #pragma unroll
            for (int n = 0; n < 16; ++n) {
                float d = tmp[n] - mean;
                vs += d * d;
            }
            #pragma unroll
            for (int o = 8; o >= 1; o >>= 1) vs += __shfl_xor(vs, o);
            float rstd = rsqrtf(vs * (1.0f / 256.0f) + 1e-5f);
            #pragma unroll
            for (int n = 0; n < 16; ++n) {
                int c = n * 16 + lr;
                float ov = (tmp[n] - mean) * rstd * gw[c] + bw[c];
                x[(size_t)rr * 256 + c] = ov;
                xb[(size_t)rr * 256 + c] = (short)f2bf(ov);
            }
        }
    }
}

// ---------------------------------------------------------------------------
// Fused FFN + residual + LayerNorm.
//   h = gelu(xb @ W1T + b1)  (kept in LDS, never hits HBM)
//   x = LN(x + h @ W2T + b2); xb = bf16(x)
// BM=64, 4 waves; wave owns 16 rows. h computed in 4 strips of 256 cols.
// GEMM1 uses swapped mfma operands so each lane holds 4 consecutive h-cols
// -> pack to bf16 and ds_write_b64 into hL (wave-private rows).
// ---------------------------------------------------------------------------
__global__ __launch_bounds__(256) void ffn_ln_kernel(
    const short* __restrict__ A,      // xb [M,256]
    const short* __restrict__ W1T,    // [1024][256]
    const short* __restrict__ W2T,    // [256][1024]
    const float* __restrict__ b1, const float* __restrict__ b2,
    const float* __restrict__ gw, const float* __restrict__ bw,
    float* __restrict__ x, short* __restrict__ xb,
    int M)
{
    __shared__ short As[64 * 256];    // 32 KB  x panel, [row][32 chunks swz]
    __shared__ short hL[64 * 256];    // 32 KB  h strip, same layout
    __shared__ short Wst[256 * 64];   // 32 KB  weight chunk [wrow][8 chunks swz]
    const int tid = threadIdx.x;
    const int bm = blockIdx.x * 64;
    const int w = tid >> 6, l = tid & 63;
    const int lr = l & 15, lq = l >> 4;

    // ---- stage As: 64 rows x 256 cols (2048 x 16B), 8 passes ----
    #pragma unroll
    for (int p = 0; p < 8; ++p) {
        int s = p * 256 + tid;
        int row = s >> 5, cs = s & 31;
        int c = cs ^ (row & 7);
        int ga = bm + row; if (ga > M - 1) ga = M - 1;
        __builtin_amdgcn_global_load_lds((const void*)(A + (size_t)ga * 256 + c * 8),
            (void*)&As[(size_t)(p * 256 + w * 64) * 8], 16, 0, 0);
    }

    f32x4 acc[16];
    #pragma unroll
    for (int n = 0; n < 16; ++n)
        #pragma unroll
        for (int j = 0; j < 4; ++j) acc[n][j] = 0.0f;

    const int srow = tid >> 3;        // Wst stage: row 0..255 over 8 passes? no:
    // Wst staging helper indices: per pass p, slot s = p*256+tid, row=s>>3, cs=s&7.

    for (int strip = 0; strip < 4; ++strip) {
        // ================= GEMM1: hacc = W1_strip x A (transposed out) ======
        f32x4 hacc[16];
        #pragma unroll
        for (int n = 0; n < 16; ++n)
            #pragma unroll
            for (int j = 0; j < 4; ++j) hacc[n][j] = 0.0f;

        const short* W1s = W1T + (size_t)(strip * 256) * 256;
        for (int kc = 0; kc < 4; ++kc) {
            __syncthreads();   // Wst free (prev readers done); 1st iter: As pending too
            #pragma unroll
            for (int p = 0; p < 8; ++p) {
                int s = p * 256 + tid;
                int row = s >> 3, cs = s & 7;
                int c = cs ^ (row & 7);
                __builtin_amdgcn_global_load_lds(
                    (const void*)(W1s + (size_t)row * 256 + kc * 64 + c * 8),
                    (void*)&Wst[(size_t)(p * 256 + w * 64) * 8], 16, 0, 0);
            }
            __syncthreads();   // Wst (and As) ready

            #pragma unroll
            for (int ks = 0; ks < 2; ++ks) {
                int arow = w * 16 + lr;
                int ac = (kc * 8 + ks * 4 + lq) ^ (arow & 7);
                bf16x8 xf = *(const bf16x8*)&As[arow * 256 + ac * 8];
                #pragma unroll
                for (int hb = 0; hb < 2; ++hb) {
                    bf16x8 wf[8];
                    #pragma unroll
                    for (int i = 0; i < 8; ++i) {
                        int wrow = (hb * 8 + i) * 16 + lr;
                        wf[i] = *(const bf16x8*)&Wst[wrow * 64 + (((ks * 4 + lq) ^ (wrow & 7))) * 8];
                    }
                    #pragma unroll
                    for (int i = 0; i < 8; ++i)
                        hacc[hb * 8 + i] = __builtin_amdgcn_mfma_f32_16x16x32_bf16(
                            wf[i], xf, hacc[hb * 8 + i], 0, 0, 0);
                }
            }
        }

        // ---- bias + GELU + pack -> hL (wave-private rows) ----
        {
            int hrow = w * 16 + lr;
            #pragma unroll
            for (int n = 0; n < 16; ++n) {
                float4 b1v = *(const float4*)(b1 + strip * 256 + n * 16 + lq * 4);
                float o0 = hacc[n][0] + b1v.x;
                float o1 = hacc[n][1] + b1v.y;
                float o2 = hacc[n][2] + b1v.z;
                float o3 = hacc[n][3] + b1v.w;
                o0 = 0.5f * o0 * (1.0f + erff(o0 * 0.70710678118654752f));
                o1 = 0.5f * o1 * (1.0f + erff(o1 * 0.70710678118654752f));
                o2 = 0.5f * o2 * (1.0f + erff(o2 * 0.70710678118654752f));
                o3 = 0.5f * o3 * (1.0f + erff(o3 * 0.70710678118654752f));
                unsigned lo = (unsigned)f2bf(o0) | ((unsigned)f2bf(o1) << 16);
                unsigned hi = (unsigned)f2bf(o2) | ((unsigned)f2bf(o3) << 16);
                int col = n * 16 + lq * 4;
                int slot = (col >> 3) ^ (hrow & 7);
                unsigned long long val = ((unsigned long long)hi << 32) | (unsigned long long)lo;
                *(unsigned long long*)((char*)hL + (size_t)hrow * 512 + slot * 16 + (col & 7) * 2) = val;
            }
        }

        // ================= GEMM2: acc += hL x W2_strip ======================
        for (int kc = 0; kc < 4; ++kc) {
            __syncthreads();   // Wst free
            #pragma unroll
            for (int p = 0; p < 8; ++p) {
                int s = p * 256 + tid;
                int row = s >> 3, cs = s & 7;
                int c = cs ^ (row & 7);
                __builtin_amdgcn_global_load_lds(
                    (const void*)(W2T + (size_t)row * 1024 + strip * 256 + kc * 64 + c * 8),
                    (void*)&Wst[(size_t)(p * 256 + w * 64) * 8], 16, 0, 0);
            }
            __syncthreads();   // Wst ready

            #pragma unroll
            for (int ks = 0; ks < 2; ++ks) {
                int hrow = w * 16 + lr;
                int hc = (kc * 8 + ks * 4 + lq) ^ (hrow & 7);
                bf16x8 hf = *(const bf16x8*)&hL[hrow * 256 + hc * 8];
                #pragma unroll
                for (int hb = 0; hb < 2; ++hb) {
                    bf16x8 wf[8];
                    #pragma unroll
                    for (int i = 0; i < 8; ++i) {
                        int wrow = (hb * 8 + i) * 16 + lr;
                        wf[i] = *(const bf16x8*)&Wst[wrow * 64 + (((ks * 4 + lq) ^ (wrow & 7))) * 8];
                    }
                    #pragma unroll
                    for (int i = 0; i < 8; ++i)
                        acc[hb * 8 + i] = __builtin_amdgcn_mfma_f32_16x16x32_bf16(
                            hf, wf[i], acc[hb * 8 + i], 0, 0, 0);
                }
            }
        }
    }

    // ---- epilogue: bias + residual + LayerNorm ----
    float bi[16];
    #pragma unroll
    for (int n = 0; n < 16; ++n) bi[n] = b2[n * 16 + lr];

    #pragma unroll
    for (int j = 0; j < 4; ++j) {
        int rr = bm + w * 16 + lq * 4 + j;
        if (rr < M) {
            float tmp[16];
            float sum = 0.0f;
            #pragma unroll
            for (int n = 0; n < 16; ++n) {
                int c = n * 16 + lr;
                float val = acc[n][j] + bi[n] + x[(size_t)rr * 256 + c];
                tmp[n] = val;
                sum += val;
            }
            #pragma unroll
            for (int o = 8; o >= 1; o >>= 1) sum += __shfl_xor(sum, o);
            float mean = sum * (1.0f / 256.0f);
            float vs = 0.0f;
            #pragma unroll
            for (int n = 0; n < 16; ++n) {
                float d = tmp[n] - mean;
                vs += d * d;
            }
            #pragma unroll
            for (int o = 8; o >= 1; o >>= 1) vs += __shfl_xor(vs, o);
            float rstd = rsqrtf(vs * (1.0f / 256.0f) + 1e-5f);
            #pragma unroll
            for (int n = 0; n < 16; ++n) {
                int c = n * 16 + lr;
                float ov = (tmp[n] - mean) * rstd * gw[c] + bw[c];
                x[(size_t)rr * 256 + c] = ov;
                xb[(size_t)rr * 256 + c] = (short)f2bf(ov);
            }
        }
    }
}

// ---------------------------------------------------------------------------
// Deformable sampling. v bf16 [CM,256], comb fp32 [CM,96], out bf16 [CM,256].
// ---------------------------------------------------------------------------
__global__ __launch_bounds__(256) void deform_attn_kernel(
    const short* __restrict__ v, const float* __restrict__ comb,
    short* __restrict__ outs)
{
    int g  = blockIdx.x * 16 + (threadIdx.x >> 4);
    int d2 = threadIdx.x & 15;
    int bn = g >> 3, h = g & 7;
    int n  = bn % NPix;
    int row = n / WW, col = n % WW;
    int base_v = (bn / NPix) * NPix;

    const float* cb = comb + (size_t)bn * 96;
    float l0 = cb[64 + h * 4 + 0], l1 = cb[64 + h * 4 + 1];
    float l2 = cb[64 + h * 4 + 2], l3 = cb[64 + h * 4 + 3];
    float mx = fmaxf(fmaxf(l0, l1), fmaxf(l2, l3));
    float e0 = __expf(l0 - mx), e1 = __expf(l1 - mx);
    float e2 = __expf(l2 - mx), e3 = __expf(l3 - mx);
    float inv = 1.0f / (e0 + e1 + e2 + e3);
    float aw[4] = {e0 * inv, e1 * inv, e2 * inv, e3 * inv};

    float acc0 = 0.0f, acc1 = 0.0f;
    size_t chb = (size_t)h * HD + d2 * 2;
    #pragma unroll
    for (int p = 0; p < 4; ++p) {
        float dx = cb[h * 8 + p * 2 + 0];
        float dy = cb[h * 8 + p * 2 + 1];
        float px = (float)col + dx;
        float py = (float)row + dy;
        float x0f = floorf(px), y0f = floorf(py);
        float wx = px - x0f, wy = py - y0f;
        int x0i = min(max((int)x0f, 0), WW - 1);
        int y0i = min(max((int)y0f, 0), HH - 1);
        int x1i = min(x0i + 1, WW - 1);
        int y1i = min(y0i + 1, HH - 1);
        unsigned u00 = *(const unsigned*)&v[(size_t)(base_v + y0i * WW + x0i) * Dm + chb];
        unsigned u01 = *(const unsigned*)&v[(size_t)(base_v + y0i * WW + x1i) * Dm + chb];
        unsigned u10 = *(const unsigned*)&v[(size_t)(base_v + y1i * WW + x0i) * Dm + chb];
        unsigned u11 = *(const unsigned*)&v[(size_t)(base_v + y1i * WW + x1i) * Dm + chb];
        float w00 = (1.0f - wx) * (1.0f - wy), w01 = wx * (1.0f - wy);
        float w10 = (1.0f - wx) * wy,          w11 = wx * wy;
        float s0 = bf2f((unsigned short)u00) * w00 + bf2f((unsigned short)u01) * w01
                 + bf2f((unsigned short)u10) * w10 + bf2f((unsigned short)u11) * w11;
        float s1 = bf2f((unsigned short)(u00 >> 16)) * w00 + bf2f((unsigned short)(u01 >> 16)) * w01
                 + bf2f((unsigned short)(u10 >> 16)) * w10 + bf2f((unsigned short)(u11 >> 16)) * w11;
        acc0 = fmaf(aw[p], s0, acc0);
        acc1 = fmaf(aw[p], s1, acc1);
    }
    unsigned outw = (unsigned)f2bf(acc0) | ((unsigned)f2bf(acc1) << 16);
    *(unsigned*)&outs[(size_t)bn * Dm + chb] = outw;
}

// ---------------------------------------------------------------------------
extern "C" void kernel_launch(void* const* d_in, const int* in_sizes, int n_in,
                              void* d_out, int out_size, void* d_ws, size_t ws_size,
                              hipStream_t stream)
{
    const float* src  = (const float*)d_in[0];
    const float* Wv   = (const float*)d_in[1];
    const float* bv   = (const float*)d_in[2];
    const float* Woff = (const float*)d_in[3];
    const float* boff = (const float*)d_in[4];
    const float* Wa   = (const float*)d_in[5];
    const float* ba   = (const float*)d_in[6];
    const float* Wo   = (const float*)d_in[7];
    const float* bo   = (const float*)d_in[8];
    const float* W1   = (const float*)d_in[9];
    const float* b1   = (const float*)d_in[10];
    const float* W2   = (const float*)d_in[11];
    const float* b2   = (const float*)d_in[12];
    const float* g1   = (const float*)d_in[13];
    const float* be1  = (const float*)d_in[14];
    const float* g2   = (const float*)d_in[15];
    const float* be2  = (const float*)d_in[16];

    float* x = (float*)d_out;   // fp32 master activations

    char* cur = (char*)d_ws;
    auto take = [&](size_t bytes) { char* p = cur; cur += (bytes + 255) & ~(size_t)255; return p; };
    short* WcatT = (short*)take((size_t)Lnum * 352 * Dm * 2);
    short* WoT   = (short*)take((size_t)Lnum * Dm * Dm * 2);
    short* W1T   = (short*)take((size_t)Lnum * Dm * FFd * 2);  // [l][1024][256]
    short* W2T   = (short*)take((size_t)Lnum * FFd * Dm * 2);  // [l][256][1024]
    float* bcat  = (float*)take((size_t)Lnum * 352 * 4);
    short* xb    = (short*)take((size_t)Mrows * Dm * 2);
    size_t fixedB = (size_t)(cur - (char*)d_ws);

    const size_t perRowB = 512 + 512 + 384;   // v, sbuf, comb
    int k = 8;
    while (k > 1 && fixedB + (size_t)k * NPix * perRowB > ws_size) k >>= 1;
    if (fixedB + (size_t)k * NPix * perRowB > ws_size) return;
    const int CM = k * NPix;
    const int nChunks = Bq / k;

    short* v    = (short*)take((size_t)CM * Dm * 2);
    short* sbuf = (short*)take((size_t)CM * Dm * 2);
    float* comb = (float*)take((size_t)CM * 96 * 4);

    repack_kernel<<<dim3(4, 4, Lnum),  256, 0, stream>>>(Wv,   WcatT, Dm,  Dm,  352 * Dm,   0);
    repack_kernel<<<dim3(1, 4, Lnum),  256, 0, stream>>>(Woff, WcatT, Dm,  64,  352 * Dm, 256);
    repack_kernel<<<dim3(1, 4, Lnum),  256, 0, stream>>>(Wa,   WcatT, Dm,  32,  352 * Dm, 320);
    repack_kernel<<<dim3(4, 4, Lnum),  256, 0, stream>>>(Wo,   WoT,   Dm,  Dm,  Dm * Dm,    0);
    repack_kernel<<<dim3(16, 4, Lnum), 256, 0, stream>>>(W1,   W1T,   Dm,  FFd, Dm * FFd,   0);
    repack_kernel<<<dim3(4, 16, Lnum), 256, 0, stream>>>(W2,   W2T,   FFd, Dm,  FFd * Dm,   0);
    bcat_kernel<<<Lnum, 352, 0, stream>>>(bv, boff, ba, bcat);

    pos_add_kernel<<<Mrows, 256, 0, stream>>>(src, x, xb);

    const int gy  = (CM + 127) / 128;
    const int gLN = (CM + 63) / 64;

    for (int l = 0; l < Lnum; ++l) {
        const short* WcatT_l = WcatT + (size_t)l * 352 * Dm;
        const short* WoT_l   = WoT   + (size_t)l * Dm * Dm;
        const short* W1T_l   = W1T   + (size_t)l * Dm * FFd;
        const short* W2T_l   = W2T   + (size_t)l * FFd * Dm;

        for (int c = 0; c < nChunks; ++c) {
            size_t rowOff = (size_t)c * CM;
            float* xc  = x  + rowOff * Dm;
            short* xbc = xb + rowOff * Dm;

            // v | comb = xb @ WcatT
            gemm_mfma_kernel<false, 2><<<dim3(3, gy), 256, 0, stream>>>(
                xbc, WcatT_l, bcat + l * 352, v, comb, CM, Dm, 352, 0);
            // sbuf = deformable sampling (bf16)
            deform_attn_kernel<<<CM / 2, 256, 0, stream>>>(v, comb, sbuf);
            // x = LN(x + sbuf @ WoT + bo); xb = bf16(x)
            gemm_ln_kernel<<<gLN, 256, 0, stream>>>(
                sbuf, WoT_l, bo + l * Dm, g1 + l * Dm, be1 + l * Dm, xc, xbc, CM, Dm);
            // x = LN(x + gelu(xb@W1T+b1)@W2T + b2); xb = bf16(x)   [h in LDS]
            ffn_ln_kernel<<<gLN, 256, 0, stream>>>(
                xbc, W1T_l, W2T_l, b1 + l * FFd, b2 + l * Dm,
                g2 + l * Dm, be2 + l * Dm, xc, xbc, CM);
        }
    }
}

// Round 6
// 2754.826 us; speedup vs baseline: 1.1018x; 1.1018x over previous
//
#include <hip/hip_runtime.h>
#include <hip/hip_bf16.h>
#include <math.h>

// Problem constants
#define Bq   8
#define NPix 10000
#define HH   100
#define WW   100
#define Dm   256
#define NH   8
#define HD   32
#define PTS  4
#define FFd  1024
#define Lnum 6
#define Mrows (Bq * NPix)   // 80000

typedef short bf16x8 __attribute__((ext_vector_type(8)));
typedef short short4v __attribute__((ext_vector_type(4)));
typedef float f32x4 __attribute__((ext_vector_type(4)));

__device__ __forceinline__ float bf2f(unsigned short u) {
    return __uint_as_float(((unsigned)u) << 16);
}
__device__ __forceinline__ unsigned short f2bf(float f) {
    unsigned x = __float_as_uint(f);
    return (unsigned short)((x + 0x7fffu + ((x >> 16) & 1u)) >> 16);  // RNE
}

// ---------------------------------------------------------------------------
// Positional encoding + add: x (fp32) and xb (bf16) = src + pe
// ---------------------------------------------------------------------------
__global__ __launch_bounds__(256) void pos_add_kernel(
    const float* __restrict__ src, float* __restrict__ x, short* __restrict__ xb)
{
    int idx = blockIdx.x * 256 + threadIdx.x;
    int c = idx & (Dm - 1);
    int n = (idx >> 8) % NPix;
    int cc = c;
    float coord;
    if (c < 128) { coord = (float)(n / WW); }
    else         { coord = (float)(n % WW); cc = c - 128; }
    int j = cc >> 1;
    float f = __expf(-logf(10000.0f) * (2.0f * (float)j) / 128.0f);
    float arg = coord * f;
    float pe = (cc & 1) ? cosf(arg) : sinf(arg);
    float val = src[idx] + pe;
    x[idx] = val;
    xb[idx] = (short)f2bf(val);
}

// ---------------------------------------------------------------------------
// Weight repack: W[l][K][N] fp32 -> Wt[l][nOff + n][K] bf16 (transpose)
// ---------------------------------------------------------------------------
__global__ __launch_bounds__(256) void repack_kernel(
    const float* __restrict__ W, short* __restrict__ Wt,
    int K, int N, int outLstride, int nOff)
{
    __shared__ float t[64][65];
    int l  = blockIdx.z;
    int k0 = blockIdx.y * 64, n0 = blockIdx.x * 64;
    const float* Wl = W + (size_t)l * K * N;
    for (int i = threadIdx.x; i < 64 * 64; i += 256) {
        int kk = i >> 6, nn = i & 63;
        float val = 0.0f;
        if (k0 + kk < K && n0 + nn < N) val = Wl[(size_t)(k0 + kk) * N + (n0 + nn)];
        t[kk][nn] = val;
    }
    __syncthreads();
    for (int i = threadIdx.x; i < 64 * 64; i += 256) {
        int nn = i >> 6, kk = i & 63;
        if (n0 + nn < N && k0 + kk < K)
            Wt[(size_t)l * outLstride + (size_t)(nOff + n0 + nn) * K + (k0 + kk)]
                = (short)f2bf(t[kk][nn]);
    }
}

// combined bias: bcat[l][352] = bv(256) | boff(64) | ba(32)
__global__ void bcat_kernel(const float* __restrict__ bv,
                            const float* __restrict__ boff,
                            const float* __restrict__ ba,
                            float* __restrict__ bcat)
{
    int l = blockIdx.x, c = threadIdx.x;
    float v;
    if (c < 256)      v = bv[l * 256 + c];
    else if (c < 320) v = boff[l * 64 + (c - 256)];
    else              v = ba[l * 32 + (c - 320)];
    bcat[l * 352 + c] = v;
}

// ---------------------------------------------------------------------------
// bf16 MFMA GEMM, 128x128 tile, 4 waves, BK=64. (WvWc path, MODE 2 split out)
// ---------------------------------------------------------------------------
template<bool GELU, int MODE>
__global__ __launch_bounds__(256) void gemm_mfma_kernel(
    const short* __restrict__ A, const short* __restrict__ Bt,
    const float* __restrict__ bias, void* __restrict__ Cv,
    float* __restrict__ C2,
    int M, int K, int Nc, int ldc)
{
    __shared__ short As[128 * 64];
    __shared__ short Bs[128 * 64];
    const int tid = threadIdx.x;

    int nwg  = gridDim.x * gridDim.y;
    int orig = blockIdx.y * gridDim.x + blockIdx.x;
    int xcd  = orig & 7, pos = orig >> 3;
    int q = nwg >> 3, r = nwg & 7;
    int flat = (xcd < r ? xcd * (q + 1) : r * (q + 1) + (xcd - r) * q) + pos;
    const int bm = (flat / gridDim.x) * 128;
    const int bn = (flat % gridDim.x) * 128;

    const int w = tid >> 6, l = tid & 63;
    const int wr = (w >> 1) * 64, wc = (w & 1) * 64;

    f32x4 acc[4][4];
    #pragma unroll
    for (int m = 0; m < 4; ++m)
        #pragma unroll
        for (int n = 0; n < 4; ++n)
            #pragma unroll
            for (int j = 0; j < 4; ++j) acc[m][n][j] = 0.0f;

    const int rl = tid >> 3;
    const int cl = tid & 7;
    const int lr = l & 15, lq = l >> 4;

    for (int k0 = 0; k0 < K; k0 += 64) {
        #pragma unroll
        for (int p = 0; p < 4; ++p) {
            int row = p * 32 + rl;
            int sc  = cl ^ (row & 7);
            int ga  = bm + row; if (ga > M - 1) ga = M - 1;
            __builtin_amdgcn_global_load_lds((const void*)(A + (size_t)ga * K + k0 + sc * 8),
                (void*)&As[(p * 32 + w * 8) * 64], 16, 0, 0);
            int gb = bn + row; if (gb > Nc - 1) gb = Nc - 1;
            __builtin_amdgcn_global_load_lds((const void*)(Bt + (size_t)gb * K + k0 + sc * 8),
                (void*)&Bs[(p * 32 + w * 8) * 64], 16, 0, 0);
        }
        __syncthreads();

        #pragma unroll
        for (int ks = 0; ks < 2; ++ks) {
            bf16x8 af[4], bfr[4];
            #pragma unroll
            for (int m = 0; m < 4; ++m) {
                int row = wr + m * 16 + lr;
                int ch  = (ks * 4 + lq) ^ (row & 7);
                af[m] = *(const bf16x8*)&As[row * 64 + ch * 8];
            }
            #pragma unroll
            for (int n = 0; n < 4; ++n) {
                int row = wc + n * 16 + lr;
                int ch  = (ks * 4 + lq) ^ (row & 7);
                bfr[n] = *(const bf16x8*)&Bs[row * 64 + ch * 8];
            }
            #pragma unroll
            for (int m = 0; m < 4; ++m)
                #pragma unroll
                for (int n = 0; n < 4; ++n)
                    acc[m][n] = __builtin_amdgcn_mfma_f32_16x16x32_bf16(
                        af[m], bfr[n], acc[m][n], 0, 0, 0);
        }
        __syncthreads();
    }

    #pragma unroll
    for (int m = 0; m < 4; ++m) {
        int row0 = bm + wr + m * 16 + lq * 4;
        #pragma unroll
        for (int n = 0; n < 4; ++n) {
            int col = bn + wc + n * 16 + lr;
            if (col >= Nc) continue;
            float bi = bias[col];
            #pragma unroll
            for (int j = 0; j < 4; ++j) {
                int rr = row0 + j;
                if (rr >= M) continue;
                float val = acc[m][n][j] + bi;
                if (GELU)
                    val = 0.5f * val * (1.0f + erff(val * 0.70710678118654752f));
                if (MODE == 1) {
                    ((short*)Cv)[(size_t)rr * ldc + col] = (short)f2bf(val);
                } else {
                    if (col < 256)
                        ((short*)Cv)[(size_t)rr * 256 + col] = (short)f2bf(val);
                    else
                        C2[(size_t)rr * 96 + (col - 256)] = val;
                }
            }
        }
    }
}

// ---------------------------------------------------------------------------
// bf16 MFMA GEMM + fused residual+LayerNorm epilogue (Wo path, K=256).
// BM=64, BN=256, 4 waves; wave owns 16 rows x 256 cols.
// ---------------------------------------------------------------------------
__global__ __launch_bounds__(256) void gemm_ln_kernel(
    const short* __restrict__ A, const short* __restrict__ Bt,
    const float* __restrict__ bias,
    const float* __restrict__ gw, const float* __restrict__ bw,
    float* __restrict__ x, short* __restrict__ xb,
    int M, int K)
{
    __shared__ short As[64 * 64];
    __shared__ short Bs[256 * 64];
    const int tid = threadIdx.x;
    const int bm = blockIdx.x * 64;
    const int w = tid >> 6, l = tid & 63;
    const int rl = tid >> 3, cl = tid & 7;
    const int lr = l & 15, lq = l >> 4;

    f32x4 acc[16];
    #pragma unroll
    for (int n = 0; n < 16; ++n)
        #pragma unroll
        for (int j = 0; j < 4; ++j) acc[n][j] = 0.0f;

    for (int k0 = 0; k0 < K; k0 += 64) {
        #pragma unroll
        for (int p = 0; p < 2; ++p) {
            int row = p * 32 + rl;
            int sc  = cl ^ (row & 7);
            int ga  = bm + row; if (ga > M - 1) ga = M - 1;
            __builtin_amdgcn_global_load_lds((const void*)(A + (size_t)ga * K + k0 + sc * 8),
                (void*)&As[(p * 32 + w * 8) * 64], 16, 0, 0);
        }
        #pragma unroll
        for (int p = 0; p < 8; ++p) {
            int row = p * 32 + rl;
            int sc  = cl ^ (row & 7);
            __builtin_amdgcn_global_load_lds((const void*)(Bt + (size_t)row * K + k0 + sc * 8),
                (void*)&Bs[(p * 32 + w * 8) * 64], 16, 0, 0);
        }
        __syncthreads();

        #pragma unroll
        for (int ks = 0; ks < 2; ++ks) {
            int arow = w * 16 + lr;
            bf16x8 af = *(const bf16x8*)&As[arow * 64 + (((ks * 4 + lq) ^ (arow & 7))) * 8];
            #pragma unroll
            for (int hb = 0; hb < 2; ++hb) {
                bf16x8 bfr[8];
                #pragma unroll
                for (int i = 0; i < 8; ++i) {
                    int brow = (hb * 8 + i) * 16 + lr;
                    bfr[i] = *(const bf16x8*)&Bs[brow * 64 + (((ks * 4 + lq) ^ (brow & 7))) * 8];
                }
                #pragma unroll
                for (int i = 0; i < 8; ++i)
                    acc[hb * 8 + i] = __builtin_amdgcn_mfma_f32_16x16x32_bf16(
                        af, bfr[i], acc[hb * 8 + i], 0, 0, 0);
            }
        }
        __syncthreads();
    }

    float bi[16];
    #pragma unroll
    for (int n = 0; n < 16; ++n) bi[n] = bias[n * 16 + lr];

    #pragma unroll
    for (int j = 0; j < 4; ++j) {
        int rr = bm + w * 16 + lq * 4 + j;
        if (rr < M) {
            float tmp[16];
            float sum = 0.0f;
            #pragma unroll
            for (int n = 0; n < 16; ++n) {
                int c = n * 16 + lr;
                float val = acc[n][j] + bi[n] + x[(size_t)rr * 256 + c];
                tmp[n] = val;
                sum += val;
            }
            #pragma unroll
            for (int o = 8; o >= 1; o >>= 1) sum += __shfl_xor(sum, o);
            float mean = sum * (1.0f / 256.0f);
            float vs = 0.0f;
            #pragma unroll
            for (int n = 0; n < 16; ++n) {
                float d = tmp[n] - mean;
                vs += d * d;
            }
            #pragma unroll
            for (int o = 8; o >= 1; o >>= 1) vs += __shfl_xor(vs, o);
            float rstd = rsqrtf(vs * (1.0f / 256.0f) + 1e-5f);
            #pragma unroll
            for (int n = 0; n < 16; ++n) {
                int c = n * 16 + lr;
                float ov = (tmp[n] - mean) * rstd * gw[c] + bw[c];
                x[(size_t)rr * 256 + c] = ov;
                xb[(size_t)rr * 256 + c] = (short)f2bf(ov);
            }
        }
    }
}

// ---------------------------------------------------------------------------
// Fused FFN + residual + LayerNorm, 512 threads (8 waves), 2-phase pipelined.
//   h = gelu(xb @ W1T + b1)  lives in LDS only.
//   x = LN(x + h @ W2T + b2); xb = bf16(x)
// BM=64. Wave w: row group g=w&3 (16 rows), col half=w>>2 (128 of 256).
// 32 phases: strip(4) x {G1 kc(4), G2 kc(4)}; Wst double-buffered so the
// stage of phase t+1 overlaps compute of phase t (T3-minimum schedule).
// ---------------------------------------------------------------------------
__global__ __launch_bounds__(512) void ffn_ln_kernel(
    const short* __restrict__ A,      // xb [M,256]
    const short* __restrict__ W1T,    // [1024][256]
    const short* __restrict__ W2T,    // [256][1024]
    const float* __restrict__ b1, const float* __restrict__ b2,
    const float* __restrict__ gw, const float* __restrict__ bw,
    float* __restrict__ x, short* __restrict__ xb,
    int M)
{
    __shared__ short As[64 * 256];      // 32 KB  x panel
    __shared__ short hL[64 * 256];      // 32 KB  h strip
    __shared__ short Wst[2][256 * 64];  // 64 KB  weight chunk, double-buffered
    __shared__ float sredA[2][64];      // LN partial sums
    __shared__ float sredB[2][64];
    const int tid  = threadIdx.x;       // 0..511
    const int w    = tid >> 6;
    const int g    = w & 3, half = w >> 2;
    const int l    = tid & 63;
    const int lr   = l & 15, lq = l >> 4;
    const int bm   = blockIdx.x * 64;

    // ---- stage As: 64 rows x 256 cols = 2048 x 16B, 4 per thread ----
    #pragma unroll
    for (int p = 0; p < 4; ++p) {
        int s = p * 512 + tid;
        int row = s >> 5, cs = s & 31;
        int c = cs ^ (row & 7);
        int ga = bm + row; if (ga > M - 1) ga = M - 1;
        __builtin_amdgcn_global_load_lds((const void*)(A + (size_t)ga * 256 + c * 8),
            (void*)&As[(size_t)(p * 512 + w * 64) * 8], 16, 0, 0);
    }

    auto stageW = [&](int ph, int buf) {
        int strip = ph >> 3, kc = ph & 3;
        bool isG2 = (ph >> 2) & 1;
        #pragma unroll
        for (int p = 0; p < 4; ++p) {
            int s = p * 512 + tid;
            int row = s >> 3, cs = s & 7;
            int c = cs ^ (row & 7);
            const short* src = isG2
                ? W2T + (size_t)row * 1024 + strip * 256 + kc * 64 + c * 8
                : W1T + (size_t)(strip * 256 + row) * 256 + kc * 64 + c * 8;
            __builtin_amdgcn_global_load_lds((const void*)src,
                (void*)&Wst[buf][(size_t)(p * 512 + w * 64) * 8], 16, 0, 0);
        }
    };
    stageW(0, 0);

    f32x4 acc[8], hacc[8];
    #pragma unroll
    for (int i = 0; i < 8; ++i)
        #pragma unroll
        for (int j = 0; j < 4; ++j) acc[i][j] = 0.0f;

    for (int ph = 0; ph < 32; ++ph) {
        const int strip = ph >> 3, kc = ph & 3;
        const bool isG2 = (ph >> 2) & 1;
        const int buf = ph & 1;

        __syncthreads();                       // Wst[buf] staged; prev reads done
        if (ph + 1 < 32) stageW(ph + 1, (ph + 1) & 1);

        if (!isG2) {
            if (kc == 0) {
                #pragma unroll
                for (int i = 0; i < 8; ++i)
                    #pragma unroll
                    for (int j = 0; j < 4; ++j) hacc[i][j] = 0.0f;
            }
            #pragma unroll
            for (int ks = 0; ks < 2; ++ks) {
                int arow = g * 16 + lr;
                int ac = (kc * 8 + ks * 4 + lq) ^ (arow & 7);
                bf16x8 xf = *(const bf16x8*)&As[arow * 256 + ac * 8];
                bf16x8 wf[8];
                #pragma unroll
                for (int i = 0; i < 8; ++i) {
                    int wrow = (half * 8 + i) * 16 + lr;
                    wf[i] = *(const bf16x8*)&Wst[buf][wrow * 64 + (((ks * 4 + lq) ^ (wrow & 7))) * 8];
                }
                #pragma unroll
                for (int i = 0; i < 8; ++i)
                    hacc[i] = __builtin_amdgcn_mfma_f32_16x16x32_bf16(
                        wf[i], xf, hacc[i], 0, 0, 0);
            }
            if (kc == 3) {
                // bias + exact GELU + pack -> hL
                int hrow = g * 16 + lr;
                #pragma unroll
                for (int i = 0; i < 8; ++i) {
                    int col = (half * 8 + i) * 16 + lq * 4;
                    float4 b1v = *(const float4*)(b1 + strip * 256 + col);
                    float o0 = hacc[i][0] + b1v.x;
                    float o1 = hacc[i][1] + b1v.y;
                    float o2 = hacc[i][2] + b1v.z;
                    float o3 = hacc[i][3] + b1v.w;
                    o0 = 0.5f * o0 * (1.0f + erff(o0 * 0.70710678118654752f));
                    o1 = 0.5f * o1 * (1.0f + erff(o1 * 0.70710678118654752f));
                    o2 = 0.5f * o2 * (1.0f + erff(o2 * 0.70710678118654752f));
                    o3 = 0.5f * o3 * (1.0f + erff(o3 * 0.70710678118654752f));
                    unsigned lo = (unsigned)f2bf(o0) | ((unsigned)f2bf(o1) << 16);
                    unsigned hi = (unsigned)f2bf(o2) | ((unsigned)f2bf(o3) << 16);
                    int slot = (col >> 3) ^ (hrow & 7);
                    unsigned long long val = ((unsigned long long)hi << 32) | (unsigned long long)lo;
                    *(unsigned long long*)((char*)hL + (size_t)hrow * 512 + slot * 16 + (col & 7) * 2) = val;
                }
            }
        } else {
            #pragma unroll
            for (int ks = 0; ks < 2; ++ks) {
                int hrow = g * 16 + lr;
                int hc = (kc * 8 + ks * 4 + lq) ^ (hrow & 7);
                bf16x8 hf = *(const bf16x8*)&hL[hrow * 256 + hc * 8];
                bf16x8 wf[8];
                #pragma unroll
                for (int i = 0; i < 8; ++i) {
                    int wrow = (half * 8 + i) * 16 + lr;
                    wf[i] = *(const bf16x8*)&Wst[buf][wrow * 64 + (((ks * 4 + lq) ^ (wrow & 7))) * 8];
                }
                #pragma unroll
                for (int i = 0; i < 8; ++i)
                    acc[i] = __builtin_amdgcn_mfma_f32_16x16x32_bf16(
                        hf, wf[i], acc[i], 0, 0, 0);
            }
        }
    }
    __syncthreads();

    // ---- epilogue: bias + residual + LayerNorm (cross-wave via sred) ----
    float bi[8], gwv[8], bwv[8];
    #pragma unroll
    for (int i = 0; i < 8; ++i) {
        int c = (half * 8 + i) * 16 + lr;
        bi[i] = b2[c]; gwv[i] = gw[c]; bwv[i] = bw[c];
    }
    const int rl64 = g * 16 + lq * 4;   // row-in-block base for this lane

    #pragma unroll
    for (int j = 0; j < 4; ++j) {
        int rr = bm + rl64 + j;
        bool valid = rr < M;
        float vals[8];
        float psum = 0.0f;
        #pragma unroll
        for (int i = 0; i < 8; ++i) {
            int c = (half * 8 + i) * 16 + lr;
            float val = acc[i][j] + bi[i] + (valid ? x[(size_t)rr * 256 + c] : 0.0f);
            vals[i] = val;
            psum += val;
        }
        #pragma unroll
        for (int o = 8; o >= 1; o >>= 1) psum += __shfl_xor(psum, o);
        if (lr == 0) sredA[half][rl64 + j] = psum;
        __syncthreads();
        float mean = (sredA[0][rl64 + j] + sredA[1][rl64 + j]) * (1.0f / 256.0f);
        float psq = 0.0f;
        #pragma unroll
        for (int i = 0; i < 8; ++i) {
            float d = vals[i] - mean;
            psq += d * d;
        }
        #pragma unroll
        for (int o = 8; o >= 1; o >>= 1) psq += __shfl_xor(psq, o);
        if (lr == 0) sredB[half][rl64 + j] = psq;
        __syncthreads();
        float rstd = rsqrtf((sredB[0][rl64 + j] + sredB[1][rl64 + j]) * (1.0f / 256.0f) + 1e-5f);
        if (valid) {
            #pragma unroll
            for (int i = 0; i < 8; ++i) {
                int c = (half * 8 + i) * 16 + lr;
                float ov = (vals[i] - mean) * rstd * gwv[i] + bwv[i];
                x[(size_t)rr * 256 + c] = ov;
                xb[(size_t)rr * 256 + c] = (short)f2bf(ov);
            }
        }
    }
}

// ---------------------------------------------------------------------------
// Deformable sampling. v bf16 [CM,256], comb fp32 [CM,96], out bf16 [CM,256].
// ---------------------------------------------------------------------------
__global__ __launch_bounds__(256) void deform_attn_kernel(
    const short* __restrict__ v, const float* __restrict__ comb,
    short* __restrict__ outs)
{
    int g  = blockIdx.x * 16 + (threadIdx.x >> 4);
    int d2 = threadIdx.x & 15;
    int bn = g >> 3, h = g & 7;
    int n  = bn % NPix;
    int row = n / WW, col = n % WW;
    int base_v = (bn / NPix) * NPix;

    const float* cb = comb + (size_t)bn * 96;
    float l0 = cb[64 + h * 4 + 0], l1 = cb[64 + h * 4 + 1];
    float l2 = cb[64 + h * 4 + 2], l3 = cb[64 + h * 4 + 3];
    float mx = fmaxf(fmaxf(l0, l1), fmaxf(l2, l3));
    float e0 = __expf(l0 - mx), e1 = __expf(l1 - mx);
    float e2 = __expf(l2 - mx), e3 = __expf(l3 - mx);
    float inv = 1.0f / (e0 + e1 + e2 + e3);
    float aw[4] = {e0 * inv, e1 * inv, e2 * inv, e3 * inv};

    float acc0 = 0.0f, acc1 = 0.0f;
    size_t chb = (size_t)h * HD + d2 * 2;
    #pragma unroll
    for (int p = 0; p < 4; ++p) {
        float dx = cb[h * 8 + p * 2 + 0];
        float dy = cb[h * 8 + p * 2 + 1];
        float px = (float)col + dx;
        float py = (float)row + dy;
        float x0f = floorf(px), y0f = floorf(py);
        float wx = px - x0f, wy = py - y0f;
        int x0i = min(max((int)x0f, 0), WW - 1);
        int y0i = min(max((int)y0f, 0), HH - 1);
        int x1i = min(x0i + 1, WW - 1);
        int y1i = min(y0i + 1, HH - 1);
        unsigned u00 = *(const unsigned*)&v[(size_t)(base_v + y0i * WW + x0i) * Dm + chb];
        unsigned u01 = *(const unsigned*)&v[(size_t)(base_v + y0i * WW + x1i) * Dm + chb];
        unsigned u10 = *(const unsigned*)&v[(size_t)(base_v + y1i * WW + x0i) * Dm + chb];
        unsigned u11 = *(const unsigned*)&v[(size_t)(base_v + y1i * WW + x1i) * Dm + chb];
        float w00 = (1.0f - wx) * (1.0f - wy), w01 = wx * (1.0f - wy);
        float w10 = (1.0f - wx) * wy,          w11 = wx * wy;
        float s0 = bf2f((unsigned short)u00) * w00 + bf2f((unsigned short)u01) * w01
                 + bf2f((unsigned short)u10) * w10 + bf2f((unsigned short)u11) * w11;
        float s1 = bf2f((unsigned short)(u00 >> 16)) * w00 + bf2f((unsigned short)(u01 >> 16)) * w01
                 + bf2f((unsigned short)(u10 >> 16)) * w10 + bf2f((unsigned short)(u11 >> 16)) * w11;
        acc0 = fmaf(aw[p], s0, acc0);
        acc1 = fmaf(aw[p], s1, acc1);
    }
    unsigned outw = (unsigned)f2bf(acc0) | ((unsigned)f2bf(acc1) << 16);
    *(unsigned*)&outs[(size_t)bn * Dm + chb] = outw;
}

// ---------------------------------------------------------------------------
extern "C" void kernel_launch(void* const* d_in, const int* in_sizes, int n_in,
                              void* d_out, int out_size, void* d_ws, size_t ws_size,
                              hipStream_t stream)
{
    const float* src  = (const float*)d_in[0];
    const float* Wv   = (const float*)d_in[1];
    const float* bv   = (const float*)d_in[2];
    const float* Woff = (const float*)d_in[3];
    const float* boff = (const float*)d_in[4];
    const float* Wa   = (const float*)d_in[5];
    const float* ba   = (const float*)d_in[6];
    const float* Wo   = (const float*)d_in[7];
    const float* bo   = (const float*)d_in[8];
    const float* W1   = (const float*)d_in[9];
    const float* b1   = (const float*)d_in[10];
    const float* W2   = (const float*)d_in[11];
    const float* b2   = (const float*)d_in[12];
    const float* g1   = (const float*)d_in[13];
    const float* be1  = (const float*)d_in[14];
    const float* g2   = (const float*)d_in[15];
    const float* be2  = (const float*)d_in[16];

    float* x = (float*)d_out;   // fp32 master activations

    char* cur = (char*)d_ws;
    auto take = [&](size_t bytes) { char* p = cur; cur += (bytes + 255) & ~(size_t)255; return p; };
    short* WcatT = (short*)take((size_t)Lnum * 352 * Dm * 2);
    short* WoT   = (short*)take((size_t)Lnum * Dm * Dm * 2);
    short* W1T   = (short*)take((size_t)Lnum * Dm * FFd * 2);  // [l][1024][256]
    short* W2T   = (short*)take((size_t)Lnum * FFd * Dm * 2);  // [l][256][1024]
    float* bcat  = (float*)take((size_t)Lnum * 352 * 4);
    short* xb    = (short*)take((size_t)Mrows * Dm * 2);
    size_t fixedB = (size_t)(cur - (char*)d_ws);

    const size_t perRowB = 512 + 512 + 384;   // v, sbuf, comb
    int k = 8;
    while (k > 1 && fixedB + (size_t)k * NPix * perRowB > ws_size) k >>= 1;
    if (fixedB + (size_t)k * NPix * perRowB > ws_size) return;
    const int CM = k * NPix;
    const int nChunks = Bq / k;

    short* v    = (short*)take((size_t)CM * Dm * 2);
    short* sbuf = (short*)take((size_t)CM * Dm * 2);
    float* comb = (float*)take((size_t)CM * 96 * 4);

    repack_kernel<<<dim3(4, 4, Lnum),  256, 0, stream>>>(Wv,   WcatT, Dm,  Dm,  352 * Dm,   0);
    repack_kernel<<<dim3(1, 4, Lnum),  256, 0, stream>>>(Woff, WcatT, Dm,  64,  352 * Dm, 256);
    repack_kernel<<<dim3(1, 4, Lnum),  256, 0, stream>>>(Wa,   WcatT, Dm,  32,  352 * Dm, 320);
    repack_kernel<<<dim3(4, 4, Lnum),  256, 0, stream>>>(Wo,   WoT,   Dm,  Dm,  Dm * Dm,    0);
    repack_kernel<<<dim3(16, 4, Lnum), 256, 0, stream>>>(W1,   W1T,   Dm,  FFd, Dm * FFd,   0);
    repack_kernel<<<dim3(4, 16, Lnum), 256, 0, stream>>>(W2,   W2T,   FFd, Dm,  FFd * Dm,   0);
    bcat_kernel<<<Lnum, 352, 0, stream>>>(bv, boff, ba, bcat);

    pos_add_kernel<<<Mrows, 256, 0, stream>>>(src, x, xb);

    const int gy  = (CM + 127) / 128;
    const int gLN = (CM + 63) / 64;

    for (int l = 0; l < Lnum; ++l) {
        const short* WcatT_l = WcatT + (size_t)l * 352 * Dm;
        const short* WoT_l   = WoT   + (size_t)l * Dm * Dm;
        const short* W1T_l   = W1T   + (size_t)l * Dm * FFd;
        const short* W2T_l   = W2T   + (size_t)l * FFd * Dm;

        for (int c = 0; c < nChunks; ++c) {
            size_t rowOff = (size_t)c * CM;
            float* xc  = x  + rowOff * Dm;
            short* xbc = xb + rowOff * Dm;

            // v | comb = xb @ WcatT
            gemm_mfma_kernel<false, 2><<<dim3(3, gy), 256, 0, stream>>>(
                xbc, WcatT_l, bcat + l * 352, v, comb, CM, Dm, 352, 0);
            // sbuf = deformable sampling (bf16)
            deform_attn_kernel<<<CM / 2, 256, 0, stream>>>(v, comb, sbuf);
            // x = LN(x + sbuf @ WoT + bo); xb = bf16(x)
            gemm_ln_kernel<<<gLN, 256, 0, stream>>>(
                sbuf, WoT_l, bo + l * Dm, g1 + l * Dm, be1 + l * Dm, xc, xbc, CM, Dm);
            // x = LN(x + gelu(xb@W1T+b1)@W2T + b2); xb = bf16(x)   [h in LDS]
            ffn_ln_kernel<<<gLN, 512, 0, stream>>>(
                xbc, W1T_l, W2T_l, b1 + l * FFd, b2 + l * Dm,
                g2 + l * Dm, be2 + l * Dm, xc, xbc, CM);
        }
    }
}